// Round 4
// baseline (17076.117 us; speedup 1.0000x reference)
//
#include <hip/hip_runtime.h>

#define BB 64
#define NN 1000
#define FF 12
#define EE 64
#define HH 128
#define OO 16

__device__ __forceinline__ float rcp_(float x){ return __builtin_amdgcn_rcpf(x); }
__device__ __forceinline__ float sigm_(float x){ return rcp_(1.0f + __expf(-x)); }
// exact algebraic form of tanh: (e^{2x}-1)/(e^{2x}+1) = 1 - 2/(e^{2x}+1)
__device__ __forceinline__ float tanh_(float x){ return 1.0f - 2.0f*rcp_(__expf(2.0f*x) + 1.0f); }

__device__ __forceinline__ float4 fma4(float4 a, float4 x, float4 w){
    a.x += x.x*w.x; a.y += x.y*w.y; a.z += x.z*w.z; a.w += x.w*w.w; return a;
}
__device__ __forceinline__ float hsum4(float4 a){ return (a.x+a.y)+(a.z+a.w); }

// 256 threads = 4 waves = 1 wave/SIMD. Lane pair (2u,2u+1) owns LSTM unit u
// (even: i,g; odd: f,o) -> gates never touch LDS (one shfl_xor(1)).
// All dot products use 4 independent accumulator chains (no -ffast-math, so
// the compiler honors written association; serial chains were costing 128-256
// cyc each in R1-R3). Outputs staged in an LDS ring, flushed once per node so
// only one barrier per 12 steps drains vmcnt. hfull stored padded (+4 per 32)
// so projection reads are bank-conflict-free.
__global__ __launch_bounds__(256, 1)
void decoder_kernel(const float* __restrict__ enc,   // (B,1,N,E)
                    const float* __restrict__ mean,  // (B,FUT,N,O)
                    const float* __restrict__ sv,    // (1,O)
                    const float* __restrict__ h0,    // (2,O)
                    const float* __restrict__ c0,    // (2,H)
                    const float* __restrict__ Wih0,  // (4H, E+O)
                    const float* __restrict__ Whh0,  // (4H, O)
                    const float* __restrict__ bih0,  // (4H)
                    const float* __restrict__ bhh0,  // (4H)
                    const float* __restrict__ Whr0,  // (O, H)
                    const float* __restrict__ Wih1,  // (4H, O)
                    const float* __restrict__ Whh1,  // (4H, O)
                    const float* __restrict__ bih1,  // (4H)
                    const float* __restrict__ bhh1,  // (4H)
                    const float* __restrict__ Whr1,  // (O, H)
                    float* __restrict__ out)         // (B,FUT,N,O)
{
    const int t = threadIdx.x;
    const int b = blockIdx.x;

    const int u  = t >> 1;          // LSTM unit 0..127
    const int m  = t & 1;           // 0: gates i,g   1: gates f,o
    const int rA = m*HH + u;        // i or f row
    const int rB = rA + 2*HH;       // g or o row

    // projection mapping (replicated per wave; only wave 0 writes):
    // output j16 = lane>>2, K-chunk q*32..q*32+31
    const int lane = t & 63;
    const int j16  = lane >> 2;
    const int q    = lane & 3;

    __shared__ __align__(16) float s_last[OO];
    __shared__ __align__(16) float s_h1[OO];
    __shared__ __align__(16) float s_h2[OO];
    __shared__ __align__(16) float s_enc[EE];
    __shared__ __align__(16) float s_nm[OO];
    __shared__ __align__(16) float s_hf[4*36];      // padded hfull: 32-block q at 36*q
    __shared__ __align__(16) float s_out[FF*OO];    // per-node output ring

    // ---- recurrent weights in registers (float4 form) ----
    float4 wAl[4], wBl[4], wAh[4], wBh[4];
    float4 w1Ai[4], w1Bi[4], w1Ah[4], w1Bh[4];
    #pragma unroll
    for (int k=0;k<4;k++){
        wAl[k]  = *(const float4*)&Wih0[(size_t)rA*(EE+OO) + EE + 4*k];
        wBl[k]  = *(const float4*)&Wih0[(size_t)rB*(EE+OO) + EE + 4*k];
        wAh[k]  = *(const float4*)&Whh0[rA*OO + 4*k];
        wBh[k]  = *(const float4*)&Whh0[rB*OO + 4*k];
        w1Ai[k] = *(const float4*)&Wih1[rA*OO + 4*k];
        w1Bi[k] = *(const float4*)&Wih1[rB*OO + 4*k];
        w1Ah[k] = *(const float4*)&Whh1[rA*OO + 4*k];
        w1Bh[k] = *(const float4*)&Whh1[rB*OO + 4*k];
    }
    const float b0A = bih0[rA] + bhh0[rA];
    const float b0B = bih0[rB] + bhh0[rB];
    const float b1A = bih1[rA] + bhh1[rA];
    const float b1B = bih1[rB] + bhh1[rB];

    // projection weights: 32 per thread per layer
    float4 wp0[8], wp1[8];
    #pragma unroll
    for (int i=0;i<8;i++){
        wp0[i] = *(const float4*)&Whr0[j16*HH + q*32 + 4*i];
        wp1[i] = *(const float4*)&Whr1[j16*HH + q*32 + 4*i];
    }

    float c1u = c0[u];
    float c2u = c0[HH + u];

    if (t < OO){
        s_last[t] = sv[t];
        s_h1[t]   = h0[t];
        s_h2[t]   = h0[OO + t];
    }

    const float* encB  = enc  + (size_t)b * NN * EE;
    const float* meanB = mean + (size_t)b * FF * NN * OO;
    float*       outB  = out  + (size_t)b * FF * NN * OO;

    // rows of Wih0 (enc part) streamed once per node (L2-resident)
    const float4* wrowA = (const float4*)(Wih0 + (size_t)rA*(EE+OO));
    const float4* wrowB = (const float4*)(Wih0 + (size_t)rB*(EE+OO));

    // ---- prefetch node 0 ----
    float4 pf_enc = make_float4(0,0,0,0);
    float  pf_nm[FF];
    if (t < 16){
        pf_enc = ((const float4*)encB)[t];
    } else if (t < 32){
        const int j = t - 16;
        #pragma unroll
        for (int ff=0; ff<FF; ++ff) pf_nm[ff] = meanB[(size_t)(ff*NN)*OO + j];
    }

    for (int n = 0; n < NN; ++n){
        // commit prefetched node data
        if (t < 16){
            ((float4*)s_enc)[t] = pf_enc;
        } else if (t < 32){
            float a0 = pf_nm[0]+pf_nm[4], a1 = pf_nm[1]+pf_nm[5];
            float a2 = pf_nm[2]+pf_nm[6], a3 = pf_nm[3]+pf_nm[7];
            a0 += pf_nm[8]; a1 += pf_nm[9]; a2 += pf_nm[10]; a3 += pf_nm[11];
            s_nm[t-16] = ((a0+a1)+(a2+a3)) * (1.0f/12.0f);
        }
        __syncthreads();                                   // B0 (per node)

        // issue prefetch for node n+1
        const int n1 = (n+1 < NN) ? (n+1) : n;
        if (t < 16){
            pf_enc = ((const float4*)encB)[n1*16 + t];
        } else if (t < 32){
            const int j = t - 16;
            #pragma unroll
            for (int ff=0; ff<FF; ++ff) pf_nm[ff] = meanB[(size_t)(ff*NN + n1)*OO + j];
        }

        // ---- pre0: bias + enc part (streamed W) + node_mean part ----
        float preA, preB;
        {
            float4 sa = make_float4(b0A, 0.f, 0.f, 0.f);
            float4 sb = make_float4(b0B, 0.f, 0.f, 0.f);
            #pragma unroll
            for (int k=0;k<16;k++){
                const float4 e = ((const float4*)s_enc)[k];
                sa = fma4(sa, e, wrowA[k]);
                sb = fma4(sb, e, wrowB[k]);
            }
            float4 nm4[4];
            #pragma unroll
            for (int k=0;k<4;k++) nm4[k] = ((const float4*)s_nm)[k];
            #pragma unroll
            for (int k=0;k<4;k++){ sa = fma4(sa, nm4[k], wAl[k]); sb = fma4(sb, nm4[k], wBl[k]); }
            preA = hsum4(sa);
            preB = hsum4(sb);
        }
        const float nmj = s_nm[j16];

        #pragma unroll 1
        for (int f = 0; f < FF; ++f){
            // ---- P1: layer-0 gates + cell (pair-fused) ----
            {
                float4 L[4], H[4];
                #pragma unroll
                for (int k=0;k<4;k++){ L[k] = ((const float4*)s_last)[k]; H[k] = ((const float4*)s_h1)[k]; }
                float4 accA = make_float4(preA, 0.f, 0.f, 0.f);
                float4 accB = make_float4(preB, 0.f, 0.f, 0.f);
                #pragma unroll
                for (int k=0;k<4;k++){
                    accA = fma4(accA, L[k], wAl[k]); accA = fma4(accA, H[k], wAh[k]);
                    accB = fma4(accB, L[k], wBl[k]); accB = fma4(accB, H[k], wBh[k]);
                }
                const float aA = hsum4(accA);
                const float aB = hsum4(accB);
                const float gA = sigm_(aA);                         // i (m=0) or f (m=1)
                const float gB = (m==0) ? tanh_(aB) : sigm_(aB);    // g (m=0) or o (m=1)
                const float sendv = (m==0) ? gA*gB : gA;
                const float recvv = __shfl_xor(sendv, 1, 64);
                const float Fv    = (m==0) ? recvv : sendv;
                const float prod  = (m==0) ? sendv : recvv;
                c1u = Fv*c1u + prod;
                if (m) s_hf[u + ((u>>5)<<2)] = gB * tanh_(c1u);
            }
            __syncthreads();                               // B1

            // ---- P2: projection h1 = Whr0 . hfull (per-wave redundant) ----
            {
                float4 acc = make_float4(0.f,0.f,0.f,0.f);
                #pragma unroll
                for (int i=0;i<8;i++){
                    const float4 h = *(const float4*)&s_hf[q*36 + 4*i];
                    acc = fma4(acc, h, wp0[i]);
                }
                float p = hsum4(acc);
                p += __shfl_xor(p, 1, 64);
                p += __shfl_xor(p, 2, 64);
                if (t < 64 && q == 0) s_h1[j16] = p;
            }
            __syncthreads();                               // B2

            // ---- P3: layer-1 gates + cell ----
            {
                float4 X[4], H[4];
                #pragma unroll
                for (int k=0;k<4;k++){ X[k] = ((const float4*)s_h1)[k]; H[k] = ((const float4*)s_h2)[k]; }
                float4 accA = make_float4(b1A, 0.f, 0.f, 0.f);
                float4 accB = make_float4(b1B, 0.f, 0.f, 0.f);
                #pragma unroll
                for (int k=0;k<4;k++){
                    accA = fma4(accA, X[k], w1Ai[k]); accA = fma4(accA, H[k], w1Ah[k]);
                    accB = fma4(accB, X[k], w1Bi[k]); accB = fma4(accB, H[k], w1Bh[k]);
                }
                const float aA = hsum4(accA);
                const float aB = hsum4(accB);
                const float gA = sigm_(aA);
                const float gB = (m==0) ? tanh_(aB) : sigm_(aB);
                const float sendv = (m==0) ? gA*gB : gA;
                const float recvv = __shfl_xor(sendv, 1, 64);
                const float Fv    = (m==0) ? recvv : sendv;
                const float prod  = (m==0) ? sendv : recvv;
                c2u = Fv*c2u + prod;
                if (m) s_hf[u + ((u>>5)<<2)] = gB * tanh_(c2u);
            }
            __syncthreads();                               // B3

            // ---- P4: projection h2 = Whr1 . hfull, state + out ring ----
            {
                float4 acc = make_float4(0.f,0.f,0.f,0.f);
                #pragma unroll
                for (int i=0;i<8;i++){
                    const float4 h = *(const float4*)&s_hf[q*36 + 4*i];
                    acc = fma4(acc, h, wp1[i]);
                }
                float p = hsum4(acc);
                p += __shfl_xor(p, 1, 64);
                p += __shfl_xor(p, 2, 64);
                if (t < 64 && q == 0){
                    s_h2[j16]   = p;
                    s_last[j16] = p;
                    s_out[f*OO + j16] = p + nmj;
                }
            }
            __syncthreads();                               // B4
        }

        // ---- flush node outputs (one vmem batch per node, off critical path) ----
        if (t < 48){
            const int ff = t >> 2, o4 = (t & 3) * 4;
            const float4 v = *(const float4*)&s_out[ff*OO + o4];
            *(float4*)&outB[(size_t)(ff*NN + n)*OO + o4] = v;
        }
    }
}

extern "C" void kernel_launch(void* const* d_in, const int* in_sizes, int n_in,
                              void* d_out, int out_size, void* d_ws, size_t ws_size,
                              hipStream_t stream) {
    const float* enc  = (const float*)d_in[0];
    const float* mean = (const float*)d_in[1];
    const float* sv   = (const float*)d_in[2];
    const float* h0   = (const float*)d_in[3];
    const float* c0   = (const float*)d_in[4];
    const float* Wih0 = (const float*)d_in[5];
    const float* Whh0 = (const float*)d_in[6];
    const float* bih0 = (const float*)d_in[7];
    const float* bhh0 = (const float*)d_in[8];
    const float* Whr0 = (const float*)d_in[9];
    const float* Wih1 = (const float*)d_in[10];
    const float* Whh1 = (const float*)d_in[11];
    const float* bih1 = (const float*)d_in[12];
    const float* bhh1 = (const float*)d_in[13];
    const float* Whr1 = (const float*)d_in[14];
    float* out = (float*)d_out;

    decoder_kernel<<<dim3(BB), dim3(256), 0, stream>>>(
        enc, mean, sv, h0, c0,
        Wih0, Whh0, bih0, bhh0, Whr0,
        Wih1, Whh1, bih1, bhh1, Whr1,
        out);
}